// Round 1
// baseline (405.974 us; speedup 1.0000x reference)
//
#include <hip/hip_runtime.h>
#include <hip/hip_bf16.h>
#include <math.h>

// Problem constants
#define NB   16      // batch
#define CC   64      // channels
#define ICH  32      // inter channels
#define TV   1600    // T*V = 64*25
#define NTV  (NB*TV) // 25600

// ---------------------------------------------------------------------------
// K1: 1x1 conv projections. x:[N,C,TV] -> Q(=k_x):[N,TV,IC], K(=q_x):[N,TV,IC],
// V(=v_x):[N,TV,IC]  (rows of 32 floats, contiguous)
// ---------------------------------------------------------------------------
__global__ __launch_bounds__(256) void proj_kernel(
    const float* __restrict__ x,
    const float* __restrict__ Wv, const float* __restrict__ bv,
    const float* __restrict__ Wk, const float* __restrict__ bk,
    const float* __restrict__ Wq, const float* __restrict__ bq,
    float* __restrict__ Q, float* __restrict__ K, float* __restrict__ V) {
  int gid = blockIdx.x * 256 + threadIdx.x;   // 0..25599
  int n = gid / TV, tv = gid % TV;
  float xr[CC];
  const float* xp = x + (size_t)n * CC * TV + tv;
#pragma unroll
  for (int c = 0; c < CC; ++c) xr[c] = xp[c * TV];
  for (int o = 0; o < ICH; ++o) {
    float av = bv[o], ak = bk[o], aq = bq[o];
#pragma unroll
    for (int c = 0; c < CC; ++c) {
      float w;
      w = Wv[o * CC + c]; av = fmaf(w, xr[c], av);
      w = Wk[o * CC + c]; ak = fmaf(w, xr[c], ak);
      w = Wq[o * CC + c]; aq = fmaf(w, xr[c], aq);
    }
    int base = (n * TV + tv) * ICH + o;
    V[base] = av;   // v_x
    Q[base] = ak;   // k_x  (rows of the attention = flash "queries")
    K[base] = aq;   // q_x  (cols of the attention = flash "keys")
  }
}

// ---------------------------------------------------------------------------
// K2: ChannelGate. One block per n.
// ---------------------------------------------------------------------------
__global__ __launch_bounds__(256) void gate_kernel(
    const float* __restrict__ x,
    const float* __restrict__ W1, const float* __restrict__ b1,
    const float* __restrict__ W2, const float* __restrict__ b2,
    float* __restrict__ gate) {
  int n = blockIdx.x;
  __shared__ float s_part[256];
  __shared__ float s_avg[CC];
  __shared__ float s_h[4];
  int t = threadIdx.x;
  int c = t >> 2, q = t & 3;
  const float* xp = x + ((size_t)n * CC + c) * TV + q * 400;
  float s = 0.f;
  for (int i = 0; i < 400; ++i) s += xp[i];
  s_part[t] = s;
  __syncthreads();
  if (t < CC) {
    s_avg[t] = (s_part[4*t] + s_part[4*t+1] + s_part[4*t+2] + s_part[4*t+3]) *
               (1.0f / (float)TV);
  }
  __syncthreads();
  if (t < 4) {
    float h = b1[t];
    for (int c2 = 0; c2 < CC; ++c2) h = fmaf(W1[t * CC + c2], s_avg[c2], h);
    s_h[t] = fmaxf(h, 0.f);
  }
  __syncthreads();
  if (t < CC) {
    float g = b2[t];
#pragma unroll
    for (int j = 0; j < 4; ++j) g = fmaf(W2[t * 4 + j], s_h[j], g);
    gate[n * CC + t] = 1.f / (1.f + __expf(-g));
  }
}

// ---------------------------------------------------------------------------
// K3: flash attention (no max subtraction -- logits bounded ~|6|).
// Block = 256 thr (4 waves). Block owns 64 rows; each wave covers all 64 rows
// (1 row/lane) over 1/4 of the s range, staged through a per-wave LDS region
// in chunks of 64 s. Partials merged through LDS (plain sums, since no
// running max). P:[N,TV,IC] normalized output.
// ---------------------------------------------------------------------------
__global__ __launch_bounds__(256) void attn_kernel(
    const float* __restrict__ Q, const float* __restrict__ K,
    const float* __restrict__ V, float* __restrict__ P) {
  __shared__ float lds[4 * 64 * 32 * 2];   // 64 KiB: per wave 4096 floats (K|V)
  int n = blockIdx.x / 25;
  int rowBase = (blockIdx.x % 25) * 64;
  int w = threadIdx.x >> 6;
  int lane = threadIdx.x & 63;
  int row = rowBase + lane;

  float q[ICH], acc[ICH];
  const float* qp = Q + ((size_t)n * TV + row) * ICH;
#pragma unroll
  for (int i = 0; i < ICH; ++i) q[i] = qp[i];
#pragma unroll
  for (int i = 0; i < ICH; ++i) acc[i] = 0.f;
  float l = 0.f;

  float* sK = lds + w * 4096;
  float* sV = sK + 2048;

  // 25 chunks of 64 s total; wave w takes chunks {w, w+4, ...}
  for (int j = 0; j < 7; ++j) {
    int ch = w + 4 * j;
    bool valid = (ch < 25);
    __syncthreads();
    if (valid) {
      const float4* kp = (const float4*)(K + ((size_t)n * TV + ch * 64 + lane) * ICH);
      const float4* vp = (const float4*)(V + ((size_t)n * TV + ch * 64 + lane) * ICH);
      float4* dK = (float4*)(sK + lane * ICH);
      float4* dV = (float4*)(sV + lane * ICH);
#pragma unroll
      for (int u = 0; u < 8; ++u) { dK[u] = kp[u]; dV[u] = vp[u]; }
    }
    __syncthreads();
    if (valid) {
      for (int s = 0; s < 64; ++s) {
        const float* kr = sK + s * ICH;
        float lg = 0.f;
#pragma unroll
        for (int i = 0; i < ICH; ++i) lg = fmaf(q[i], kr[i], lg);
        float p = __expf(lg);
        l += p;
        const float* vr = sV + s * ICH;
#pragma unroll
        for (int i = 0; i < ICH; ++i) acc[i] = fmaf(p, vr[i], acc[i]);
      }
    }
  }

  // merge the 4 wave-partials through LDS (plain sums)
  __syncthreads();
  float* mp = lds + (w * 64 + lane) * 33;   // 8448 floats used, fits
#pragma unroll
  for (int i = 0; i < ICH; ++i) mp[i] = acc[i];
  mp[32] = l;
  __syncthreads();
  if (w == 0) {
    float ta[ICH];
    float tl = 0.f;
#pragma unroll
    for (int i = 0; i < ICH; ++i) ta[i] = 0.f;
#pragma unroll
    for (int ww = 0; ww < 4; ++ww) {
      const float* sp = lds + (ww * 64 + lane) * 33;
#pragma unroll
      for (int i = 0; i < ICH; ++i) ta[i] += sp[i];
      tl += sp[32];
    }
    float inv = 1.f / tl;
    float* pp = P + ((size_t)n * TV + row) * ICH;
#pragma unroll
    for (int i = 0; i < ICH; ++i) pp[i] = ta[i] * inv;
  }
}

// ---------------------------------------------------------------------------
// K4: trans-conv on the fly + per-block partial sums for BN batch stats.
// PS:[100][128] = {sum_y[64], sum_y2[64]} per block.
// ---------------------------------------------------------------------------
__global__ __launch_bounds__(256) void stats_kernel(
    const float* __restrict__ P, const float* __restrict__ Wt,
    const float* __restrict__ bt, float* __restrict__ PS) {
  int gid = blockIdx.x * 256 + threadIdx.x;
  int n = gid / TV, tv = gid % TV;
  float p[ICH];
  const float* pp = P + ((size_t)n * TV + tv) * ICH;
#pragma unroll
  for (int i = 0; i < ICH; ++i) p[i] = pp[i];
  __shared__ float sp[2][4][CC];
  int w = threadIdx.x >> 6, lane = threadIdx.x & 63;
  for (int co = 0; co < CC; ++co) {
    float y = bt[co];
#pragma unroll
    for (int i = 0; i < ICH; ++i) y = fmaf(Wt[co * ICH + i], p[i], y);
    float y2 = y * y;
#pragma unroll
    for (int off = 32; off >= 1; off >>= 1) {
      y  += __shfl_down(y, off, 64);
      y2 += __shfl_down(y2, off, 64);
    }
    if (lane == 0) { sp[0][w][co] = y; sp[1][w][co] = y2; }
  }
  __syncthreads();
  if (threadIdx.x < 128) {
    int which = threadIdx.x >> 6;
    int co = threadIdx.x & 63;
    float s = sp[which][0][co] + sp[which][1][co] +
              sp[which][2][co] + sp[which][3][co];
    PS[blockIdx.x * 128 + which * CC + co] = s;
  }
}

// ---------------------------------------------------------------------------
// K5: finalize BN stats -> scale/shift per channel. 1 block, 64 threads.
// ---------------------------------------------------------------------------
__global__ void finalize_stats(
    const float* __restrict__ PS, const float* __restrict__ gamma,
    const float* __restrict__ beta, float* __restrict__ SS) {
  int c = threadIdx.x;
  float s = 0.f, ss = 0.f;
  for (int b = 0; b < 100; ++b) {
    s  += PS[b * 128 + c];
    ss += PS[b * 128 + 64 + c];
  }
  float mean = s * (1.f / (float)NTV);
  float var  = ss * (1.f / (float)NTV) - mean * mean;
  float scale = rsqrtf(var + 1e-5f) * gamma[c];
  SS[c] = scale;
  SS[64 + c] = beta[c] - mean * scale;
}

// ---------------------------------------------------------------------------
// K6: recompute y, apply BN + gate + residual.
// ---------------------------------------------------------------------------
__global__ __launch_bounds__(256) void apply_kernel(
    const float* __restrict__ P, const float* __restrict__ Wt,
    const float* __restrict__ bt, const float* __restrict__ SS,
    const float* __restrict__ gate, const float* __restrict__ x,
    float* __restrict__ out) {
  int gid = blockIdx.x * 256 + threadIdx.x;
  int n = gid / TV, tv = gid % TV;
  float p[ICH];
  const float* pp = P + ((size_t)n * TV + tv) * ICH;
#pragma unroll
  for (int i = 0; i < ICH; ++i) p[i] = pp[i];
  for (int co = 0; co < CC; ++co) {
    float y = bt[co];
#pragma unroll
    for (int i = 0; i < ICH; ++i) y = fmaf(Wt[co * ICH + i], p[i], y);
    size_t idx = ((size_t)n * CC + co) * TV + tv;
    out[idx] = gate[n * CC + co] * fmaf(y, SS[co], SS[64 + co]) + x[idx];
  }
}

// ---------------------------------------------------------------------------
extern "C" void kernel_launch(void* const* d_in, const int* in_sizes, int n_in,
                              void* d_out, int out_size, void* d_ws, size_t ws_size,
                              hipStream_t stream) {
  const float* x     = (const float*)d_in[0];
  const float* Wv    = (const float*)d_in[1];
  const float* bv    = (const float*)d_in[2];
  const float* Wk    = (const float*)d_in[3];
  const float* bk    = (const float*)d_in[4];
  const float* Wq    = (const float*)d_in[5];
  const float* bq    = (const float*)d_in[6];
  const float* Wt    = (const float*)d_in[7];
  const float* bt    = (const float*)d_in[8];
  const float* gamma = (const float*)d_in[9];
  const float* beta  = (const float*)d_in[10];
  const float* W1    = (const float*)d_in[11];
  const float* b1    = (const float*)d_in[12];
  const float* W2    = (const float*)d_in[13];
  const float* b2    = (const float*)d_in[14];
  float* out = (float*)d_out;
  float* ws  = (float*)d_ws;

  // workspace layout (floats)
  float* Q    = ws;                    // 819200  (k_x rows)
  float* K    = ws + 819200;           // 819200  (q_x rows over s)
  float* V    = ws + 1638400;          // 819200  (v_x rows)
  float* P    = ws + 2457600;          // 819200  attention output [N,TV,IC]
  float* PS   = ws + 3276800;          // 12800   per-block BN partials
  float* SS   = ws + 3289600;          // 128     scale/shift
  float* GATE = ws + 3289728;          // 1024
  // total 3290752 floats = ~13.2 MB

  proj_kernel<<<100, 256, 0, stream>>>(x, Wv, bv, Wk, bk, Wq, bq, Q, K, V);
  gate_kernel<<<NB, 256, 0, stream>>>(x, W1, b1, W2, b2, GATE);
  attn_kernel<<<NB * 25, 256, 0, stream>>>(Q, K, V, P);
  stats_kernel<<<100, 256, 0, stream>>>(P, Wt, bt, PS);
  finalize_stats<<<1, 64, 0, stream>>>(PS, gamma, beta, SS);
  apply_kernel<<<100, 256, 0, stream>>>(P, Wt, bt, SS, GATE, x, out);
}

// Round 2
// 286.528 us; speedup vs baseline: 1.4169x; 1.4169x over previous
//
#include <hip/hip_runtime.h>
#include <hip/hip_bf16.h>
#include <math.h>

// Problem constants
#define NB   16      // batch
#define CC   64      // channels
#define ICH  32      // inter channels
#define TV   1600    // T*V = 64*25
#define NTV  (NB*TV) // 25600

typedef __bf16 bf16x8 __attribute__((ext_vector_type(8)));
typedef float  f32x4  __attribute__((ext_vector_type(4)));

// ---------------------------------------------------------------------------
// K1: 1x1 conv projections -> split-bf16 operand arrays for MFMA attention.
//  Qh/Ql = k_x  (attention rows, A operand)        [N,TV,32] bf16
//  Kh/Kl = q_x  (attention cols, B operand for QK) [N,TV,32] bf16
//  VTh/VTl = v_x transposed (B operand for PV)     [N,32,TV] bf16
// Thread = (tv, o-group of 8). Grid 400x256.
// ---------------------------------------------------------------------------
__global__ __launch_bounds__(256) void proj_kernel(
    const float* __restrict__ x,
    const float* __restrict__ Wv, const float* __restrict__ bv,
    const float* __restrict__ Wk, const float* __restrict__ bk,
    const float* __restrict__ Wq, const float* __restrict__ bq,
    __bf16* __restrict__ Qh, __bf16* __restrict__ Ql,
    __bf16* __restrict__ Kh, __bf16* __restrict__ Kl,
    __bf16* __restrict__ VTh, __bf16* __restrict__ VTl) {
  int gid = blockIdx.x * 256 + threadIdx.x;   // 0..102399
  int og = gid & 3;                            // o-group (8 outputs)
  int tvIdx = gid >> 2;                        // 0..25599
  int n = tvIdx / TV, tv = tvIdx % TV;

  float xr[CC];
  const float* xp = x + (size_t)n * CC * TV + tv;
#pragma unroll
  for (int c = 0; c < CC; ++c) xr[c] = xp[c * TV];

  bf16x8 qh, ql, kh, kl;
  int ob = og * 8;
#pragma unroll
  for (int j = 0; j < 8; ++j) {
    int o = ob + j;
    float av = bv[o], ak = bk[o], aq = bq[o];
#pragma unroll
    for (int c = 0; c < CC; ++c) {
      av = fmaf(Wv[o * CC + c], xr[c], av);
      ak = fmaf(Wk[o * CC + c], xr[c], ak);
      aq = fmaf(Wq[o * CC + c], xr[c], aq);
    }
    __bf16 h;
    h = (__bf16)ak; qh[j] = h; ql[j] = (__bf16)(ak - (float)h);   // k_x -> rows
    h = (__bf16)aq; kh[j] = h; kl[j] = (__bf16)(aq - (float)h);   // q_x -> cols
    h = (__bf16)av;                                               // v_x -> VT
    VTh[((size_t)(n * ICH + o)) * TV + tv] = h;
    VTl[((size_t)(n * ICH + o)) * TV + tv] = (__bf16)(av - (float)h);
  }
  size_t base = ((size_t)(n * TV + tv)) * ICH + ob;
  *(bf16x8*)(Qh + base) = qh;
  *(bf16x8*)(Ql + base) = ql;
  *(bf16x8*)(Kh + base) = kh;
  *(bf16x8*)(Kl + base) = kl;
}

// ---------------------------------------------------------------------------
// K2: ChannelGate. One block per n. float4 loads.
// ---------------------------------------------------------------------------
__global__ __launch_bounds__(256) void gate_kernel(
    const float* __restrict__ x,
    const float* __restrict__ W1, const float* __restrict__ b1,
    const float* __restrict__ W2, const float* __restrict__ b2,
    float* __restrict__ gate) {
  int n = blockIdx.x;
  __shared__ float s_part[256];
  __shared__ float s_avg[CC];
  __shared__ float s_h[4];
  int t = threadIdx.x;
  int c = t >> 2, q = t & 3;
  const float4* xp = (const float4*)(x + ((size_t)n * CC + c) * TV + q * 400);
  float s = 0.f;
  for (int i = 0; i < 100; ++i) {
    float4 v = xp[i];
    s += v.x + v.y + v.z + v.w;
  }
  s_part[t] = s;
  __syncthreads();
  if (t < CC) {
    s_avg[t] = (s_part[4*t] + s_part[4*t+1] + s_part[4*t+2] + s_part[4*t+3]) *
               (1.0f / (float)TV);
  }
  __syncthreads();
  if (t < 4) {
    float h = b1[t];
    for (int c2 = 0; c2 < CC; ++c2) h = fmaf(W1[t * CC + c2], s_avg[c2], h);
    s_h[t] = fmaxf(h, 0.f);
  }
  __syncthreads();
  if (t < CC) {
    float g = b2[t];
#pragma unroll
    for (int j = 0; j < 4; ++j) g = fmaf(W2[t * 4 + j], s_h[j], g);
    gate[n * CC + t] = 1.f / (1.f + __expf(-g));
  }
}

// ---------------------------------------------------------------------------
// K3: MFMA flash attention, split-bf16 (hi/lo) for fp32-grade accuracy.
// One wave per block, 16 rows per wave, grid = N * 100 = 1600 blocks.
// No max subtraction (logits bounded ~|6|). All K/V fragments are contiguous
// 16B global loads (L2-resident); only exp(S) round-trips through LDS to
// convert C-layout -> A-layout. P:[N,TV,32] fp32 normalized output.
// ---------------------------------------------------------------------------
__global__ __launch_bounds__(64) void attn_kernel(
    const __bf16* __restrict__ Qh, const __bf16* __restrict__ Ql,
    const __bf16* __restrict__ Kh, const __bf16* __restrict__ Kl,
    const __bf16* __restrict__ VTh, const __bf16* __restrict__ VTl,
    float* __restrict__ P) {
  __shared__ float Pbuf[16][68];   // 16 rows x 64 s, pad to 68 (2-way = free)
  int n = blockIdx.x / 100;
  int row0 = (blockIdx.x % 100) * 16;
  int lane = threadIdx.x;
  int m = lane & 15, q = lane >> 4;

  size_t qbase = ((size_t)(n * TV + row0 + m)) * ICH + q * 8;
  bf16x8 aQh = *(const bf16x8*)(Qh + qbase);
  bf16x8 aQl = *(const bf16x8*)(Ql + qbase);

  f32x4 o0 = {0.f, 0.f, 0.f, 0.f};
  f32x4 o1 = {0.f, 0.f, 0.f, 0.f};
  float lsum = 0.f;

  for (int ch = 0; ch < 25; ++ch) {
    int s0 = ch * 64;
    // ---- QK^T: 4 subtiles of 16 s, K=32 in one MFMA, 3 MFMAs for split ----
#pragma unroll
    for (int st = 0; st < 4; ++st) {
      size_t kbase = ((size_t)(n * TV + s0 + st * 16 + m)) * ICH + q * 8;
      bf16x8 bKh = *(const bf16x8*)(Kh + kbase);
      bf16x8 bKl = *(const bf16x8*)(Kl + kbase);
      f32x4 acc = {0.f, 0.f, 0.f, 0.f};
      acc = __builtin_amdgcn_mfma_f32_16x16x32_bf16(aQh, bKh, acc, 0, 0, 0);
      acc = __builtin_amdgcn_mfma_f32_16x16x32_bf16(aQh, bKl, acc, 0, 0, 0);
      acc = __builtin_amdgcn_mfma_f32_16x16x32_bf16(aQl, bKh, acc, 0, 0, 0);
      // C layout: row = q*4+r, col = st*16+m
#pragma unroll
      for (int r = 0; r < 4; ++r)
        Pbuf[q * 4 + r][st * 16 + m] = __expf(acc[r]);
    }
    __syncthreads();
    // ---- P*V: 2 k-chunks of 32 s; A-frag read from LDS, split to bf16 ----
#pragma unroll
    for (int kc = 0; kc < 2; ++kc) {
      float pv[8];
#pragma unroll
      for (int j = 0; j < 8; ++j) {
        pv[j] = Pbuf[m][kc * 32 + q * 8 + j];   // A layout: row=m, k=q*8+j
        lsum += pv[j];
      }
      bf16x8 aPh, aPl;
#pragma unroll
      for (int j = 0; j < 8; ++j) {
        __bf16 h = (__bf16)pv[j];
        aPh[j] = h;
        aPl[j] = (__bf16)(pv[j] - (float)h);
      }
#pragma unroll
      for (int ict = 0; ict < 2; ++ict) {
        size_t vbase = ((size_t)(n * ICH + ict * 16 + m)) * TV + s0 + kc * 32 + q * 8;
        bf16x8 bVh = *(const bf16x8*)(VTh + vbase);
        bf16x8 bVl = *(const bf16x8*)(VTl + vbase);
        f32x4 acc = (ict == 0) ? o0 : o1;
        acc = __builtin_amdgcn_mfma_f32_16x16x32_bf16(aPh, bVh, acc, 0, 0, 0);
        acc = __builtin_amdgcn_mfma_f32_16x16x32_bf16(aPh, bVl, acc, 0, 0, 0);
        acc = __builtin_amdgcn_mfma_f32_16x16x32_bf16(aPl, bVh, acc, 0, 0, 0);
        if (ict == 0) o0 = acc; else o1 = acc;
      }
    }
    __syncthreads();   // Pbuf reused next chunk
  }

  // lane (m,q) holds partial row-m sum over its s-subset; reduce over quads
  lsum += __shfl_xor(lsum, 16, 64);
  lsum += __shfl_xor(lsum, 32, 64);

  // O is in C layout: row = q*4+r, col(ic) = m / 16+m. Normalize and store.
#pragma unroll
  for (int r = 0; r < 4; ++r) {
    float lr = __shfl(lsum, q * 4 + r, 64);   // lane (q*4+r) has row's total
    float inv = 1.f / lr;
    size_t pb = ((size_t)(n * TV + row0 + q * 4 + r)) * ICH;
    P[pb + m]      = o0[r] * inv;
    P[pb + 16 + m] = o1[r] * inv;
  }
}

// ---------------------------------------------------------------------------
// K4: trans-conv recompute + BN partial sums. Block = (cg of 16 channels,
// 256 tv). Grid 400. PS2[400][32] = {sum_y[16], sum_y2[16]}.
// ---------------------------------------------------------------------------
__global__ __launch_bounds__(256) void stats_kernel(
    const float* __restrict__ P, const float* __restrict__ Wt,
    const float* __restrict__ bt, float* __restrict__ PS2) {
  int cg = blockIdx.x / 100;
  int tb = blockIdx.x % 100;
  int tvIdx = tb * 256 + threadIdx.x;
  int n = tvIdx / TV, tv = tvIdx % TV;

  union { f32x4 v[8]; float f[32]; } p;
  const f32x4* pp = (const f32x4*)(P + ((size_t)(n * TV + tv)) * ICH);
#pragma unroll
  for (int u = 0; u < 8; ++u) p.v[u] = pp[u];

  __shared__ float red[2][4][16];
  int w = threadIdx.x >> 6, lane = threadIdx.x & 63;
#pragma unroll
  for (int j = 0; j < 16; ++j) {
    int c = cg * 16 + j;
    float y = bt[c];
#pragma unroll
    for (int i = 0; i < ICH; ++i) y = fmaf(Wt[c * ICH + i], p.f[i], y);
    float y2 = y * y;
#pragma unroll
    for (int off = 32; off >= 1; off >>= 1) {
      y  += __shfl_xor(y,  off, 64);
      y2 += __shfl_xor(y2, off, 64);
    }
    if (lane == 0) { red[0][w][j] = y; red[1][w][j] = y2; }
  }
  __syncthreads();
  if (threadIdx.x < 32) {
    int which = threadIdx.x >> 4, j = threadIdx.x & 15;
    float s = red[which][0][j] + red[which][1][j] +
              red[which][2][j] + red[which][3][j];
    PS2[blockIdx.x * 32 + which * 16 + j] = s;
  }
}

// ---------------------------------------------------------------------------
// K5: finalize BN stats -> scale/shift per channel. 1 block, 64 threads.
// ---------------------------------------------------------------------------
__global__ void finalize_stats(
    const float* __restrict__ PS2, const float* __restrict__ gamma,
    const float* __restrict__ beta, float* __restrict__ SS) {
  int c = threadIdx.x;
  int cg = c >> 4, j = c & 15;
  float s = 0.f, ss = 0.f;
  for (int b = 0; b < 100; ++b) {
    int base = (cg * 100 + b) * 32;
    s  += PS2[base + j];
    ss += PS2[base + 16 + j];
  }
  float mean = s * (1.f / (float)NTV);
  float var  = ss * (1.f / (float)NTV) - mean * mean;
  float scale = rsqrtf(var + 1e-5f) * gamma[c];
  SS[c] = scale;
  SS[64 + c] = beta[c] - mean * scale;
}

// ---------------------------------------------------------------------------
// K6: recompute y for 16 channels, apply BN + gate + residual. Grid 400.
// ---------------------------------------------------------------------------
__global__ __launch_bounds__(256) void apply_kernel(
    const float* __restrict__ P, const float* __restrict__ Wt,
    const float* __restrict__ bt, const float* __restrict__ SS,
    const float* __restrict__ gate, const float* __restrict__ x,
    float* __restrict__ out) {
  int cg = blockIdx.x / 100;
  int tb = blockIdx.x % 100;
  int tvIdx = tb * 256 + threadIdx.x;
  int n = tvIdx / TV, tv = tvIdx % TV;

  union { f32x4 v[8]; float f[32]; } p;
  const f32x4* pp = (const f32x4*)(P + ((size_t)(n * TV + tv)) * ICH);
#pragma unroll
  for (int u = 0; u < 8; ++u) p.v[u] = pp[u];

#pragma unroll
  for (int j = 0; j < 16; ++j) {
    int c = cg * 16 + j;
    float y = bt[c];
#pragma unroll
    for (int i = 0; i < ICH; ++i) y = fmaf(Wt[c * ICH + i], p.f[i], y);
    size_t idx = ((size_t)(n * CC + c)) * TV + tv;
    out[idx] = gate[n * CC + c] * fmaf(y, SS[c], SS[64 + c]) + x[idx];
  }
}

// ---------------------------------------------------------------------------
extern "C" void kernel_launch(void* const* d_in, const int* in_sizes, int n_in,
                              void* d_out, int out_size, void* d_ws, size_t ws_size,
                              hipStream_t stream) {
  const float* x     = (const float*)d_in[0];
  const float* Wv    = (const float*)d_in[1];
  const float* bv    = (const float*)d_in[2];
  const float* Wk    = (const float*)d_in[3];
  const float* bk    = (const float*)d_in[4];
  const float* Wq    = (const float*)d_in[5];
  const float* bq    = (const float*)d_in[6];
  const float* Wt    = (const float*)d_in[7];
  const float* bt    = (const float*)d_in[8];
  const float* gamma = (const float*)d_in[9];
  const float* beta  = (const float*)d_in[10];
  const float* W1    = (const float*)d_in[11];
  const float* b1    = (const float*)d_in[12];
  const float* W2    = (const float*)d_in[13];
  const float* b2    = (const float*)d_in[14];
  float* out = (float*)d_out;
  char* ws = (char*)d_ws;

  // workspace layout (bytes) — total 13,163,008 B (same as round 1, proven fit)
  const size_t E = 819200;          // N*TV*ICH
  __bf16* Qh  = (__bf16*)(ws);
  __bf16* Ql  = (__bf16*)(ws + 2*E);
  __bf16* Kh  = (__bf16*)(ws + 4*E);
  __bf16* Kl  = (__bf16*)(ws + 6*E);
  __bf16* VTh = (__bf16*)(ws + 8*E);
  __bf16* VTl = (__bf16*)(ws + 10*E);
  float*  P   = (float*) (ws + 12*E);            // 819200 floats
  float*  PS2 = (float*) (ws + 12*E + 4*E);      // 12800 floats
  float*  SS  = (float*) (ws + 12*E + 4*E + 51200);
  float*  GATE= (float*) (ws + 12*E + 4*E + 51200 + 512);

  proj_kernel<<<400, 256, 0, stream>>>(x, Wv, bv, Wk, bk, Wq, bq,
                                       Qh, Ql, Kh, Kl, VTh, VTl);
  gate_kernel<<<NB, 256, 0, stream>>>(x, W1, b1, W2, b2, GATE);
  attn_kernel<<<NB * 100, 64, 0, stream>>>(Qh, Ql, Kh, Kl, VTh, VTl, P);
  stats_kernel<<<400, 256, 0, stream>>>(P, Wt, bt, PS2);
  finalize_stats<<<1, 64, 0, stream>>>(PS2, gamma, beta, SS);
  apply_kernel<<<400, 256, 0, stream>>>(P, Wt, bt, SS, GATE, x, out);
}

// Round 3
// 203.157 us; speedup vs baseline: 1.9983x; 1.4104x over previous
//
#include <hip/hip_runtime.h>
#include <hip/hip_bf16.h>
#include <math.h>

// Problem constants
#define NB   16      // batch
#define CC   64      // channels
#define ICH  32      // inter channels
#define TV   1600    // T*V = 64*25
#define NTV  (NB*TV) // 25600

typedef __bf16 bf16x8 __attribute__((ext_vector_type(8)));
typedef float  f32x4  __attribute__((ext_vector_type(4)));

// ---------------------------------------------------------------------------
// K1: 1x1 conv projections -> split-bf16 operand arrays for MFMA attention.
// Grid 1200 = 100 tv-tiles x {3 proj x 4 o-groups}. lane<->tv (coalesced x),
// o wave-uniform (scalar weight loads).
//  Qh/Ql = k_x  [N,TV,32]   Kh/Kl = q_x [N,TV,32]   VTh/VTl = v_x^T [N,32,TV]
// ---------------------------------------------------------------------------
__global__ __launch_bounds__(256) void proj_kernel(
    const float* __restrict__ x,
    const float* __restrict__ Wv, const float* __restrict__ bv,
    const float* __restrict__ Wk, const float* __restrict__ bk,
    const float* __restrict__ Wq, const float* __restrict__ bq,
    __bf16* __restrict__ Qh, __bf16* __restrict__ Ql,
    __bf16* __restrict__ Kh, __bf16* __restrict__ Kl,
    __bf16* __restrict__ VTh, __bf16* __restrict__ VTl) {
  int tile = blockIdx.x / 12;
  int sub  = blockIdx.x % 12;        // p*4 + og
  int p = sub >> 2, og = sub & 3;
  int tvIdx = tile * 256 + threadIdx.x;   // 0..25599
  int n = tvIdx / TV, tv = tvIdx % TV;

  const float* W; const float* B;
  if (p == 0)      { W = Wv; B = bv; }
  else if (p == 1) { W = Wk; B = bk; }
  else             { W = Wq; B = bq; }
  int ob = og * 8;

  float acc[8];
#pragma unroll
  for (int j = 0; j < 8; ++j) acc[j] = B[ob + j];

  const float* xp = x + (size_t)n * CC * TV + tv;
#pragma unroll 16
  for (int c = 0; c < CC; ++c) {
    float xc = xp[c * TV];
#pragma unroll
    for (int j = 0; j < 8; ++j)
      acc[j] = fmaf(W[(ob + j) * CC + c], xc, acc[j]);
  }

  if (p == 0) {          // v_x -> transposed, split
#pragma unroll
    for (int j = 0; j < 8; ++j) {
      int o = ob + j;
      __bf16 h = (__bf16)acc[j];
      size_t idx = ((size_t)(n * ICH + o)) * TV + tv;
      VTh[idx] = h;
      VTl[idx] = (__bf16)(acc[j] - (float)h);
    }
  } else {
    bf16x8 hh, ll;
#pragma unroll
    for (int j = 0; j < 8; ++j) {
      __bf16 h = (__bf16)acc[j];
      hh[j] = h;
      ll[j] = (__bf16)(acc[j] - (float)h);
    }
    size_t base = ((size_t)(n * TV + tv)) * ICH + ob;
    if (p == 1) { *(bf16x8*)(Qh + base) = hh; *(bf16x8*)(Ql + base) = ll; }
    else        { *(bf16x8*)(Kh + base) = hh; *(bf16x8*)(Kl + base) = ll; }
  }
}

// ---------------------------------------------------------------------------
// K2: ChannelGate phase 1: per-(n, 16-channel group) mean over TV.
// Grid 64 = n*4+cq. thread = (c16 = t>>4, l = t&15). AVG[n*64+c] (in d_out).
// ---------------------------------------------------------------------------
__global__ __launch_bounds__(256) void gate_avg_kernel(
    const float* __restrict__ x, float* __restrict__ AVG) {
  int n = blockIdx.x >> 2, cq = blockIdx.x & 3;
  int c16 = threadIdx.x >> 4, l = threadIdx.x & 15;
  int c = cq * 16 + c16;
  const float4* xp = (const float4*)(x + ((size_t)n * CC + c) * TV) + l;
  float s = 0.f;
#pragma unroll
  for (int i = 0; i < 25; ++i) {
    float4 v = xp[i * 16];
    s += v.x + v.y + v.z + v.w;
  }
#pragma unroll
  for (int off = 8; off >= 1; off >>= 1) s += __shfl_down(s, off, 16);
  if (l == 0) AVG[n * CC + c] = s * (1.0f / (float)TV);
}

// ---------------------------------------------------------------------------
// K3: MFMA flash attention, split-bf16 (hi/lo). One wave per block,
// 16 rows per wave, grid = N*100. P:[N,TV,32] fp32 normalized.
// ---------------------------------------------------------------------------
__global__ __launch_bounds__(64) void attn_kernel(
    const __bf16* __restrict__ Qh, const __bf16* __restrict__ Ql,
    const __bf16* __restrict__ Kh, const __bf16* __restrict__ Kl,
    const __bf16* __restrict__ VTh, const __bf16* __restrict__ VTl,
    float* __restrict__ P) {
  __shared__ float Pbuf[16][68];
  int n = blockIdx.x / 100;
  int row0 = (blockIdx.x % 100) * 16;
  int lane = threadIdx.x;
  int m = lane & 15, q = lane >> 4;

  size_t qbase = ((size_t)(n * TV + row0 + m)) * ICH + q * 8;
  bf16x8 aQh = *(const bf16x8*)(Qh + qbase);
  bf16x8 aQl = *(const bf16x8*)(Ql + qbase);

  f32x4 o0 = {0.f, 0.f, 0.f, 0.f};
  f32x4 o1 = {0.f, 0.f, 0.f, 0.f};
  float lsum = 0.f;

  for (int ch = 0; ch < 25; ++ch) {
    int s0 = ch * 64;
#pragma unroll
    for (int st = 0; st < 4; ++st) {
      size_t kbase = ((size_t)(n * TV + s0 + st * 16 + m)) * ICH + q * 8;
      bf16x8 bKh = *(const bf16x8*)(Kh + kbase);
      bf16x8 bKl = *(const bf16x8*)(Kl + kbase);
      f32x4 acc = {0.f, 0.f, 0.f, 0.f};
      acc = __builtin_amdgcn_mfma_f32_16x16x32_bf16(aQh, bKh, acc, 0, 0, 0);
      acc = __builtin_amdgcn_mfma_f32_16x16x32_bf16(aQh, bKl, acc, 0, 0, 0);
      acc = __builtin_amdgcn_mfma_f32_16x16x32_bf16(aQl, bKh, acc, 0, 0, 0);
#pragma unroll
      for (int r = 0; r < 4; ++r)
        Pbuf[q * 4 + r][st * 16 + m] = __expf(acc[r]);
    }
    __syncthreads();
#pragma unroll
    for (int kc = 0; kc < 2; ++kc) {
      float pv[8];
#pragma unroll
      for (int j = 0; j < 8; ++j) {
        pv[j] = Pbuf[m][kc * 32 + q * 8 + j];
        lsum += pv[j];
      }
      bf16x8 aPh, aPl;
#pragma unroll
      for (int j = 0; j < 8; ++j) {
        __bf16 h = (__bf16)pv[j];
        aPh[j] = h;
        aPl[j] = (__bf16)(pv[j] - (float)h);
      }
#pragma unroll
      for (int ict = 0; ict < 2; ++ict) {
        size_t vbase = ((size_t)(n * ICH + ict * 16 + m)) * TV + s0 + kc * 32 + q * 8;
        bf16x8 bVh = *(const bf16x8*)(VTh + vbase);
        bf16x8 bVl = *(const bf16x8*)(VTl + vbase);
        f32x4 acc = (ict == 0) ? o0 : o1;
        acc = __builtin_amdgcn_mfma_f32_16x16x32_bf16(aPh, bVh, acc, 0, 0, 0);
        acc = __builtin_amdgcn_mfma_f32_16x16x32_bf16(aPh, bVl, acc, 0, 0, 0);
        acc = __builtin_amdgcn_mfma_f32_16x16x32_bf16(aPl, bVh, acc, 0, 0, 0);
        if (ict == 0) o0 = acc; else o1 = acc;
      }
    }
    __syncthreads();
  }

  lsum += __shfl_xor(lsum, 16, 64);
  lsum += __shfl_xor(lsum, 32, 64);

#pragma unroll
  for (int r = 0; r < 4; ++r) {
    float lr = __shfl(lsum, q * 4 + r, 64);
    float inv = 1.f / lr;
    size_t pb = ((size_t)(n * TV + row0 + q * 4 + r)) * ICH;
    P[pb + m]      = o0[r] * inv;
    P[pb + 16 + m] = o1[r] * inv;
  }
}

// ---------------------------------------------------------------------------
// K4: trans-conv recompute + BN partial sums. Grid 800 = cg(8 ch)*100 + tb.
// PS2[800][16] = {sum_y[8], sum_y2[8]}.
// ---------------------------------------------------------------------------
__global__ __launch_bounds__(256) void stats_kernel(
    const float* __restrict__ P, const float* __restrict__ Wt,
    const float* __restrict__ bt, float* __restrict__ PS2) {
  int cg = blockIdx.x / 100;
  int tb = blockIdx.x % 100;
  int tvIdx = tb * 256 + threadIdx.x;
  int n = tvIdx / TV, tv = tvIdx % TV;

  union { f32x4 v[8]; float f[32]; } p;
  const f32x4* pp = (const f32x4*)(P + ((size_t)(n * TV + tv)) * ICH);
#pragma unroll
  for (int u = 0; u < 8; ++u) p.v[u] = pp[u];

  __shared__ float red[2][4][8];
  int w = threadIdx.x >> 6, lane = threadIdx.x & 63;
#pragma unroll
  for (int j = 0; j < 8; ++j) {
    int c = cg * 8 + j;
    float y = bt[c];
#pragma unroll
    for (int i = 0; i < ICH; ++i) y = fmaf(Wt[c * ICH + i], p.f[i], y);
    float y2 = y * y;
#pragma unroll
    for (int off = 32; off >= 1; off >>= 1) {
      y  += __shfl_xor(y,  off, 64);
      y2 += __shfl_xor(y2, off, 64);
    }
    if (lane == 0) { red[0][w][j] = y; red[1][w][j] = y2; }
  }
  __syncthreads();
  if (threadIdx.x < 16) {
    int which = threadIdx.x >> 3, j = threadIdx.x & 7;
    float s = red[which][0][j] + red[which][1][j] +
              red[which][2][j] + red[which][3][j];
    PS2[blockIdx.x * 16 + which * 8 + j] = s;
  }
}

// ---------------------------------------------------------------------------
// K5: finalize BN stats -> SS, plus ChannelGate MLP -> GATE.
// 1 block, 128 threads. AVG lives in d_out (overwritten later by apply).
// ---------------------------------------------------------------------------
__global__ __launch_bounds__(128) void finalize_stats(
    const float* __restrict__ PS2, const float* __restrict__ gamma,
    const float* __restrict__ beta, const float* __restrict__ AVG,
    const float* __restrict__ W1, const float* __restrict__ b1,
    const float* __restrict__ W2, const float* __restrict__ b2,
    float* __restrict__ SS, float* __restrict__ GATE) {
  int t = threadIdx.x;
  __shared__ float sh[NB][4];
  if (t < 64) {
    int c = t, cg = c >> 3, j = c & 7;
    float s = 0.f, ss = 0.f;
    for (int b = 0; b < 100; ++b) {
      int base = (cg * 100 + b) * 16;
      s  += PS2[base + j];
      ss += PS2[base + 8 + j];
    }
    float mean = s * (1.f / (float)NTV);
    float var  = ss * (1.f / (float)NTV) - mean * mean;
    float scale = rsqrtf(var + 1e-5f) * gamma[c];
    SS[c] = scale;
    SS[64 + c] = beta[c] - mean * scale;
    // MLP hidden: t -> (n = t>>2, jj = t&3)
    int n = t >> 2, jj = t & 3;
    float h = b1[jj];
    for (int c2 = 0; c2 < CC; ++c2)
      h = fmaf(W1[jj * CC + c2], AVG[n * CC + c2], h);
    sh[n][jj] = fmaxf(h, 0.f);
  }
  __syncthreads();
#pragma unroll
  for (int u = 0; u < 8; ++u) {
    int idx = t * 8 + u;
    int n = idx >> 6, c = idx & 63;
    float g = b2[c];
#pragma unroll
    for (int jj = 0; jj < 4; ++jj) g = fmaf(W2[c * 4 + jj], sh[n][jj], g);
    GATE[idx] = 1.f / (1.f + __expf(-g));
  }
}

// ---------------------------------------------------------------------------
// K6: recompute y for 8 channels, apply BN + gate + residual. Grid 800.
// ---------------------------------------------------------------------------
__global__ __launch_bounds__(256) void apply_kernel(
    const float* __restrict__ P, const float* __restrict__ Wt,
    const float* __restrict__ bt, const float* __restrict__ SS,
    const float* __restrict__ gate, const float* __restrict__ x,
    float* __restrict__ out) {
  int cg = blockIdx.x / 100;
  int tb = blockIdx.x % 100;
  int tvIdx = tb * 256 + threadIdx.x;
  int n = tvIdx / TV, tv = tvIdx % TV;

  union { f32x4 v[8]; float f[32]; } p;
  const f32x4* pp = (const f32x4*)(P + ((size_t)(n * TV + tv)) * ICH);
#pragma unroll
  for (int u = 0; u < 8; ++u) p.v[u] = pp[u];

#pragma unroll
  for (int j = 0; j < 8; ++j) {
    int c = cg * 8 + j;
    float y = bt[c];
#pragma unroll
    for (int i = 0; i < ICH; ++i) y = fmaf(Wt[c * ICH + i], p.f[i], y);
    size_t idx = ((size_t)(n * CC + c)) * TV + tv;
    out[idx] = gate[n * CC + c] * fmaf(y, SS[c], SS[64 + c]) + x[idx];
  }
}

// ---------------------------------------------------------------------------
extern "C" void kernel_launch(void* const* d_in, const int* in_sizes, int n_in,
                              void* d_out, int out_size, void* d_ws, size_t ws_size,
                              hipStream_t stream) {
  const float* x     = (const float*)d_in[0];
  const float* Wv    = (const float*)d_in[1];
  const float* bv    = (const float*)d_in[2];
  const float* Wk    = (const float*)d_in[3];
  const float* bk    = (const float*)d_in[4];
  const float* Wq    = (const float*)d_in[5];
  const float* bq    = (const float*)d_in[6];
  const float* Wt    = (const float*)d_in[7];
  const float* bt    = (const float*)d_in[8];
  const float* gamma = (const float*)d_in[9];
  const float* beta  = (const float*)d_in[10];
  const float* W1    = (const float*)d_in[11];
  const float* b1    = (const float*)d_in[12];
  const float* W2    = (const float*)d_in[13];
  const float* b2    = (const float*)d_in[14];
  float* out = (float*)d_out;
  char* ws = (char*)d_ws;

  // workspace layout (bytes) — total 13,163,008 B (same as round 1/2, fits)
  const size_t E = 819200;
  __bf16* Qh  = (__bf16*)(ws);
  __bf16* Ql  = (__bf16*)(ws + 2*E);
  __bf16* Kh  = (__bf16*)(ws + 4*E);
  __bf16* Kl  = (__bf16*)(ws + 6*E);
  __bf16* VTh = (__bf16*)(ws + 8*E);
  __bf16* VTl = (__bf16*)(ws + 10*E);
  float*  P   = (float*) (ws + 12*E);                    // 819200 floats
  float*  PS2 = (float*) (ws + 12*E + 4*E);              // 12800 floats
  float*  SS  = (float*) (ws + 12*E + 4*E + 51200);      // 128 floats
  float*  GATE= (float*) (ws + 12*E + 4*E + 51200 + 512);// 1024 floats
  float*  AVG = out;   // scratch: fully overwritten by apply_kernel at the end

  proj_kernel<<<1200, 256, 0, stream>>>(x, Wv, bv, Wk, bk, Wq, bq,
                                        Qh, Ql, Kh, Kl, VTh, VTl);
  gate_avg_kernel<<<64, 256, 0, stream>>>(x, AVG);
  attn_kernel<<<NB * 100, 64, 0, stream>>>(Qh, Ql, Kh, Kl, VTh, VTl, P);
  stats_kernel<<<800, 256, 0, stream>>>(P, Wt, bt, PS2);
  finalize_stats<<<1, 128, 0, stream>>>(PS2, gamma, beta, AVG,
                                        W1, b1, W2, b2, SS, GATE);
  apply_kernel<<<800, 256, 0, stream>>>(P, Wt, bt, SS, GATE, x, out);
}

// Round 4
// 184.900 us; speedup vs baseline: 2.1956x; 1.0987x over previous
//
#include <hip/hip_runtime.h>
#include <hip/hip_bf16.h>
#include <math.h>

// Problem constants
#define NB   16      // batch
#define CC   64      // channels
#define ICH  32      // inter channels
#define TV   1600    // T*V = 64*25
#define NTV  (NB*TV) // 25600

typedef __bf16 bf16x8 __attribute__((ext_vector_type(8)));
typedef float  f32x4  __attribute__((ext_vector_type(4)));

// ---------------------------------------------------------------------------
// K1: 1x1 conv projections -> split-bf16 operand arrays for MFMA attention,
// with ChannelGate average fused in as blocks 1200..1263.
// Blocks 0..1199: 100 tv-tiles x {3 proj x 4 o-groups}. lane<->tv (coalesced),
// o wave-uniform (scalar weight loads).
//  Qh/Ql = k_x  [N,TV,32]   Kh/Kl = q_x [N,TV,32]   VTh/VTl = v_x^T [N,32,TV]
// ---------------------------------------------------------------------------
__global__ __launch_bounds__(256) void proj_gate_kernel(
    const float* __restrict__ x,
    const float* __restrict__ Wv, const float* __restrict__ bv,
    const float* __restrict__ Wk, const float* __restrict__ bk,
    const float* __restrict__ Wq, const float* __restrict__ bq,
    __bf16* __restrict__ Qh, __bf16* __restrict__ Ql,
    __bf16* __restrict__ Kh, __bf16* __restrict__ Kl,
    __bf16* __restrict__ VTh, __bf16* __restrict__ VTl,
    float* __restrict__ AVG) {
  if (blockIdx.x >= 1200) {
    // ---- ChannelGate phase 1: per-(n, c) mean over TV ----
    int b = blockIdx.x - 1200;
    int n = b >> 2, cq = b & 3;
    int c16 = threadIdx.x >> 4, l = threadIdx.x & 15;
    int c = cq * 16 + c16;
    const float4* xp = (const float4*)(x + ((size_t)n * CC + c) * TV) + l;
    float s = 0.f;
#pragma unroll
    for (int i = 0; i < 25; ++i) {
      float4 v = xp[i * 16];
      s += v.x + v.y + v.z + v.w;
    }
#pragma unroll
    for (int off = 8; off >= 1; off >>= 1) s += __shfl_down(s, off, 16);
    if (l == 0) AVG[n * CC + c] = s * (1.0f / (float)TV);
    return;
  }

  int tile = blockIdx.x / 12;
  int sub  = blockIdx.x % 12;        // p*4 + og
  int p = sub >> 2, og = sub & 3;
  int tvIdx = tile * 256 + threadIdx.x;   // 0..25599
  int n = tvIdx / TV, tv = tvIdx % TV;

  const float* W; const float* B;
  if (p == 0)      { W = Wv; B = bv; }
  else if (p == 1) { W = Wk; B = bk; }
  else             { W = Wq; B = bq; }
  int ob = og * 8;

  float acc[8];
#pragma unroll
  for (int j = 0; j < 8; ++j) acc[j] = B[ob + j];

  const float* xp = x + (size_t)n * CC * TV + tv;
#pragma unroll 16
  for (int c = 0; c < CC; ++c) {
    float xc = xp[c * TV];
#pragma unroll
    for (int j = 0; j < 8; ++j)
      acc[j] = fmaf(W[(ob + j) * CC + c], xc, acc[j]);
  }

  if (p == 0) {          // v_x -> transposed, split
#pragma unroll
    for (int j = 0; j < 8; ++j) {
      int o = ob + j;
      __bf16 h = (__bf16)acc[j];
      size_t idx = ((size_t)(n * ICH + o)) * TV + tv;
      VTh[idx] = h;
      VTl[idx] = (__bf16)(acc[j] - (float)h);
    }
  } else {
    bf16x8 hh, ll;
#pragma unroll
    for (int j = 0; j < 8; ++j) {
      __bf16 h = (__bf16)acc[j];
      hh[j] = h;
      ll[j] = (__bf16)(acc[j] - (float)h);
    }
    size_t base = ((size_t)(n * TV + tv)) * ICH + ob;
    if (p == 1) { *(bf16x8*)(Qh + base) = hh; *(bf16x8*)(Ql + base) = ll; }
    else        { *(bf16x8*)(Kh + base) = hh; *(bf16x8*)(Kl + base) = ll; }
  }
}

// ---------------------------------------------------------------------------
// K3: MFMA flash attention, split-bf16 (hi/lo). 4 waves per block; each wave
// handles the SAME 16 rows over 1/4 of the s-chunks with a PRIVATE LDS Pbuf
// slice (no intra-loop __syncthreads: in-wave DS ordering + lgkmcnt(0)).
// Wave partials (o0,o1,lsum) merged through LDS at the end (plain sums --
// no max subtraction, logits bounded ~|6|). Grid = N*100. P:[N,TV,32] fp32.
// ---------------------------------------------------------------------------
__global__ __launch_bounds__(256) void attn_kernel(
    const __bf16* __restrict__ Qh, const __bf16* __restrict__ Ql,
    const __bf16* __restrict__ Kh, const __bf16* __restrict__ Kl,
    const __bf16* __restrict__ VTh, const __bf16* __restrict__ VTl,
    float* __restrict__ P) {
  __shared__ float lds[4 * 16 * 68];   // 17408 B: per-wave 16x68 Pbuf slice
  int n = blockIdx.x / 100;
  int row0 = (blockIdx.x % 100) * 16;
  int w = threadIdx.x >> 6;
  int lane = threadIdx.x & 63;
  int m = lane & 15, q = lane >> 4;

  float* Pw = lds + w * 1088;          // this wave's 16x68 buffer

  size_t qbase = ((size_t)(n * TV + row0 + m)) * ICH + q * 8;
  bf16x8 aQh = *(const bf16x8*)(Qh + qbase);
  bf16x8 aQl = *(const bf16x8*)(Ql + qbase);

  f32x4 o0 = {0.f, 0.f, 0.f, 0.f};
  f32x4 o1 = {0.f, 0.f, 0.f, 0.f};
  float lsum = 0.f;

  int nch = (w == 3) ? 7 : 6;          // chunk residue (3-w): w=3 -> 7 chunks
  for (int j = 0; j < nch; ++j) {
    int ch = 4 * j + (3 - w);
    int s0 = ch * 64;
    // ---- QK^T: 4 subtiles of 16 s; 3 MFMAs each (split hi/lo) ----
#pragma unroll
    for (int st = 0; st < 4; ++st) {
      size_t kbase = ((size_t)(n * TV + s0 + st * 16 + m)) * ICH + q * 8;
      bf16x8 bKh = *(const bf16x8*)(Kh + kbase);
      bf16x8 bKl = *(const bf16x8*)(Kl + kbase);
      f32x4 acc = {0.f, 0.f, 0.f, 0.f};
      acc = __builtin_amdgcn_mfma_f32_16x16x32_bf16(aQh, bKh, acc, 0, 0, 0);
      acc = __builtin_amdgcn_mfma_f32_16x16x32_bf16(aQh, bKl, acc, 0, 0, 0);
      acc = __builtin_amdgcn_mfma_f32_16x16x32_bf16(aQl, bKh, acc, 0, 0, 0);
      // C layout: row = q*4+r, col = st*16+m
#pragma unroll
      for (int r = 0; r < 4; ++r)
        Pw[(q * 4 + r) * 68 + st * 16 + m] = __expf(acc[r]);
    }
    // in-wave DS write->read ordering (cross-lane, same wave)
    asm volatile("s_waitcnt lgkmcnt(0)" ::: "memory");
    // ---- P*V: 2 k-chunks of 32 s; A-frag from own LDS slice ----
#pragma unroll
    for (int kc = 0; kc < 2; ++kc) {
      const f32x4* prow = (const f32x4*)(Pw + m * 68 + kc * 32);
      f32x4 pa = prow[q * 2];
      f32x4 pb = prow[q * 2 + 1];
      float pv[8] = {pa.x, pa.y, pa.z, pa.w, pb.x, pb.y, pb.z, pb.w};
      bf16x8 aPh, aPl;
#pragma unroll
      for (int jj = 0; jj < 8; ++jj) {
        lsum += pv[jj];
        __bf16 h = (__bf16)pv[jj];
        aPh[jj] = h;
        aPl[jj] = (__bf16)(pv[jj] - (float)h);
      }
#pragma unroll
      for (int ict = 0; ict < 2; ++ict) {
        size_t vbase = ((size_t)(n * ICH + ict * 16 + m)) * TV + s0 + kc * 32 + q * 8;
        bf16x8 bVh = *(const bf16x8*)(VTh + vbase);
        bf16x8 bVl = *(const bf16x8*)(VTl + vbase);
        f32x4 acc = (ict == 0) ? o0 : o1;
        acc = __builtin_amdgcn_mfma_f32_16x16x32_bf16(aPh, bVh, acc, 0, 0, 0);
        acc = __builtin_amdgcn_mfma_f32_16x16x32_bf16(aPh, bVl, acc, 0, 0, 0);
        acc = __builtin_amdgcn_mfma_f32_16x16x32_bf16(aPl, bVh, acc, 0, 0, 0);
        if (ict == 0) o0 = acc; else o1 = acc;
      }
    }
    // keep next iteration's DS writes behind this iteration's DS reads
    asm volatile("" ::: "memory");
  }

  // wave-local row sums: lane(m,q) -> row m total for this wave's s-subset
  lsum += __shfl_xor(lsum, 16, 64);
  lsum += __shfl_xor(lsum, 32, 64);

  // ---- merge 4 wave-partials through LDS (reuse Pbuf area) ----
  __syncthreads();                      // all waves done with their Pbuf
  float* mp = lds + (w * 64 + lane) * 9;  // 2304 floats used
#pragma unroll
  for (int r = 0; r < 4; ++r) { mp[r] = o0[r]; mp[4 + r] = o1[r]; }
  mp[8] = lsum;
  __syncthreads();
  if (w == 0) {
#pragma unroll
    for (int ww = 1; ww < 4; ++ww) {
      const float* sp = lds + (ww * 64 + lane) * 9;
#pragma unroll
      for (int r = 0; r < 4; ++r) { o0[r] += sp[r]; o1[r] += sp[4 + r]; }
      lsum += sp[8];
    }
#pragma unroll
    for (int r = 0; r < 4; ++r) {
      float lr = __shfl(lsum, q * 4 + r, 64);   // lane (q*4+r): row total
      float inv = 1.f / lr;
      size_t pb = ((size_t)(n * TV + row0 + q * 4 + r)) * ICH;
      P[pb + m]      = o0[r] * inv;
      P[pb + 16 + m] = o1[r] * inv;
    }
  }
}

// ---------------------------------------------------------------------------
// K4: trans-conv recompute + BN partial sums. Grid 800 = cg(8 ch)*100 + tb.
// PS2[800][16] = {sum_y[8], sum_y2[8]}.
// ---------------------------------------------------------------------------
__global__ __launch_bounds__(256) void stats_kernel(
    const float* __restrict__ P, const float* __restrict__ Wt,
    const float* __restrict__ bt, float* __restrict__ PS2) {
  int cg = blockIdx.x / 100;
  int tb = blockIdx.x % 100;
  int tvIdx = tb * 256 + threadIdx.x;
  int n = tvIdx / TV, tv = tvIdx % TV;

  union { f32x4 v[8]; float f[32]; } p;
  const f32x4* pp = (const f32x4*)(P + ((size_t)(n * TV + tv)) * ICH);
#pragma unroll
  for (int u = 0; u < 8; ++u) p.v[u] = pp[u];

  __shared__ float red[2][4][8];
  int w = threadIdx.x >> 6, lane = threadIdx.x & 63;
#pragma unroll
  for (int j = 0; j < 8; ++j) {
    int c = cg * 8 + j;
    float y = bt[c];
#pragma unroll
    for (int i = 0; i < ICH; ++i) y = fmaf(Wt[c * ICH + i], p.f[i], y);
    float y2 = y * y;
#pragma unroll
    for (int off = 32; off >= 1; off >>= 1) {
      y  += __shfl_xor(y,  off, 64);
      y2 += __shfl_xor(y2, off, 64);
    }
    if (lane == 0) { red[0][w][j] = y; red[1][w][j] = y2; }
  }
  __syncthreads();
  if (threadIdx.x < 16) {
    int which = threadIdx.x >> 3, j = threadIdx.x & 7;
    float s = red[which][0][j] + red[which][1][j] +
              red[which][2][j] + red[which][3][j];
    PS2[blockIdx.x * 16 + which * 8 + j] = s;
  }
}

// ---------------------------------------------------------------------------
// K5: finalize BN stats -> SS, plus ChannelGate MLP -> GATE.
// 1 block, 128 threads. AVG lives in d_out (overwritten later by apply).
// ---------------------------------------------------------------------------
__global__ __launch_bounds__(128) void finalize_stats(
    const float* __restrict__ PS2, const float* __restrict__ gamma,
    const float* __restrict__ beta, const float* __restrict__ AVG,
    const float* __restrict__ W1, const float* __restrict__ b1,
    const float* __restrict__ W2, const float* __restrict__ b2,
    float* __restrict__ SS, float* __restrict__ GATE) {
  int t = threadIdx.x;
  __shared__ float sh[NB][4];
  if (t < 64) {
    int c = t, cg = c >> 3, j = c & 7;
    float s = 0.f, ss = 0.f;
    for (int b = 0; b < 100; ++b) {
      int base = (cg * 100 + b) * 16;
      s  += PS2[base + j];
      ss += PS2[base + 8 + j];
    }
    float mean = s * (1.f / (float)NTV);
    float var  = ss * (1.f / (float)NTV) - mean * mean;
    float scale = rsqrtf(var + 1e-5f) * gamma[c];
    SS[c] = scale;
    SS[64 + c] = beta[c] - mean * scale;
    // MLP hidden: t -> (n = t>>2, jj = t&3)
    int n = t >> 2, jj = t & 3;
    float h = b1[jj];
    for (int c2 = 0; c2 < CC; ++c2)
      h = fmaf(W1[jj * CC + c2], AVG[n * CC + c2], h);
    sh[n][jj] = fmaxf(h, 0.f);
  }
  __syncthreads();
#pragma unroll
  for (int u = 0; u < 8; ++u) {
    int idx = t * 8 + u;
    int n = idx >> 6, c = idx & 63;
    float g = b2[c];
#pragma unroll
    for (int jj = 0; jj < 4; ++jj) g = fmaf(W2[c * 4 + jj], sh[n][jj], g);
    GATE[idx] = 1.f / (1.f + __expf(-g));
  }
}

// ---------------------------------------------------------------------------
// K6: recompute y for 8 channels, apply BN + gate + residual. Grid 800.
// ---------------------------------------------------------------------------
__global__ __launch_bounds__(256) void apply_kernel(
    const float* __restrict__ P, const float* __restrict__ Wt,
    const float* __restrict__ bt, const float* __restrict__ SS,
    const float* __restrict__ gate, const float* __restrict__ x,
    float* __restrict__ out) {
  int cg = blockIdx.x / 100;
  int tb = blockIdx.x % 100;
  int tvIdx = tb * 256 + threadIdx.x;
  int n = tvIdx / TV, tv = tvIdx % TV;

  union { f32x4 v[8]; float f[32]; } p;
  const f32x4* pp = (const f32x4*)(P + ((size_t)(n * TV + tv)) * ICH);
#pragma unroll
  for (int u = 0; u < 8; ++u) p.v[u] = pp[u];

#pragma unroll
  for (int j = 0; j < 8; ++j) {
    int c = cg * 8 + j;
    float y = bt[c];
#pragma unroll
    for (int i = 0; i < ICH; ++i) y = fmaf(Wt[c * ICH + i], p.f[i], y);
    size_t idx = ((size_t)(n * CC + c)) * TV + tv;
    out[idx] = gate[n * CC + c] * fmaf(y, SS[c], SS[64 + c]) + x[idx];
  }
}

// ---------------------------------------------------------------------------
extern "C" void kernel_launch(void* const* d_in, const int* in_sizes, int n_in,
                              void* d_out, int out_size, void* d_ws, size_t ws_size,
                              hipStream_t stream) {
  const float* x     = (const float*)d_in[0];
  const float* Wv    = (const float*)d_in[1];
  const float* bv    = (const float*)d_in[2];
  const float* Wk    = (const float*)d_in[3];
  const float* bk    = (const float*)d_in[4];
  const float* Wq    = (const float*)d_in[5];
  const float* bq    = (const float*)d_in[6];
  const float* Wt    = (const float*)d_in[7];
  const float* bt    = (const float*)d_in[8];
  const float* gamma = (const float*)d_in[9];
  const float* beta  = (const float*)d_in[10];
  const float* W1    = (const float*)d_in[11];
  const float* b1    = (const float*)d_in[12];
  const float* W2    = (const float*)d_in[13];
  const float* b2    = (const float*)d_in[14];
  float* out = (float*)d_out;
  char* ws = (char*)d_ws;

  // workspace layout (bytes) — total 13,163,008 B (same as rounds 1-3, fits)
  const size_t E = 819200;
  __bf16* Qh  = (__bf16*)(ws);
  __bf16* Ql  = (__bf16*)(ws + 2*E);
  __bf16* Kh  = (__bf16*)(ws + 4*E);
  __bf16* Kl  = (__bf16*)(ws + 6*E);
  __bf16* VTh = (__bf16*)(ws + 8*E);
  __bf16* VTl = (__bf16*)(ws + 10*E);
  float*  P   = (float*) (ws + 12*E);                    // 819200 floats
  float*  PS2 = (float*) (ws + 12*E + 4*E);              // 12800 floats
  float*  SS  = (float*) (ws + 12*E + 4*E + 51200);      // 128 floats
  float*  GATE= (float*) (ws + 12*E + 4*E + 51200 + 512);// 1024 floats
  float*  AVG = out;   // scratch: fully overwritten by apply_kernel at the end

  proj_gate_kernel<<<1264, 256, 0, stream>>>(x, Wv, bv, Wk, bk, Wq, bq,
                                             Qh, Ql, Kh, Kl, VTh, VTl, AVG);
  attn_kernel<<<NB * 100, 256, 0, stream>>>(Qh, Ql, Kh, Kl, VTh, VTl, P);
  stats_kernel<<<800, 256, 0, stream>>>(P, Wt, bt, PS2);
  finalize_stats<<<1, 128, 0, stream>>>(PS2, gamma, beta, AVG,
                                        W1, b1, W2, b2, SS, GATE);
  apply_kernel<<<800, 256, 0, stream>>>(P, Wt, bt, SS, GATE, x, out);
}